// Round 3
// baseline (111.447 us; speedup 1.0000x reference)
//
#include <hip/hip_runtime.h>

// Problem: B=512, L=512, A=20, C=8, 1 first conv + 8 rest conv blocks. All f32.
// Key algebra:
//  - _row term underflows to exactly 0 (exp(-5000) == 0.0f).
//  - x is one-hot => (xp+_column)[b,k,p] = U[aa[b,p], k], U = I + V (V from lpm/pm).
//  - conv/pool stack is linear => out = W_eff (8x512) applied per (b,k) row.
//  - out[b,k,c] = sum_i T[b,c,i] * U[i,k],  T[b,c,i] = sum_{p: aa[b,p]=i} W_eff[c,p].

// ---------------- Kernel 1: U matrix (20x20) ----------------
__global__ void build_U(const float* __restrict__ lpm,
                        const float* __restrict__ pm,
                        float* __restrict__ U){
    int t = threadIdx.x;
    for (int idx = t; idx < 400; idx += 64){
        int i = idx / 20, k = idx % 20;
        float v = 0.f;
        if (k != 19 && k != i){
            int r = (k > i) ? i : k;
            int c = (k > i) ? k : i;
            float l = fminf(fmaxf(lpm[r*20 + c], 1e-3f), 1.0f);
            v = l * pm[r*20 + c];
        }
        U[idx] = v + ((i == k) ? 1.0f : 0.0f);
    }
}

// ---------------- Kernel 2: W_eff via impulse responses ----------------
// Block p computes the conv stack on e_p (length-512 impulse), yielding
// W_eff[:, p] (8 floats). conv(k=3,pad=1) + avgpool(2) fused into a
// 4-tap stride-2 conv with taps [w0, w0+w1, w1+w2, w2] * 0.5.
__global__ __launch_bounds__(64) void build_Weff(
        const float* __restrict__ wf,   // (8,1,3)
        const float* __restrict__ wr,   // (8,8,8,3)
        float* __restrict__ Weff){      // (8,512)
    int p = blockIdx.x;
    int t = threadIdx.x;
    __shared__ float s[512];
    __shared__ float bufA[8*256];
    __shared__ float bufB[8*128];
    __shared__ float taps[8*8*4];

    for (int j = t; j < 512; j += 64) s[j] = (j == p) ? 1.f : 0.f;
    if (t < 8){
        float w0 = wf[t*3+0], w1 = wf[t*3+1], w2 = wf[t*3+2];
        taps[t*4+0] = 0.5f*w0;
        taps[t*4+1] = 0.5f*(w0+w1);
        taps[t*4+2] = 0.5f*(w1+w2);
        taps[t*4+3] = 0.5f*w2;
    }
    __syncthreads();
    // stage 1: 1 -> 8 channels, len 512 -> 256
    for (int idx = t; idx < 8*256; idx += 64){
        int c = idx >> 8, q = idx & 255;
        int j = 2*q;
        float sm1 = (j >= 1) ? s[j-1] : 0.f;
        float s0 = s[j];
        float s1 = s[j+1];
        float s2 = (j+2 < 512) ? s[j+2] : 0.f;
        const float* tp = &taps[c*4];
        bufA[c*256 + q] = tp[0]*sm1 + tp[1]*s0 + tp[2]*s1 + tp[3]*s2;
    }
    __syncthreads();
    // NOTE: `float* bufs[2] = {bufA, bufB};` hits "unsupported expression in
    // static initializer" (LDS addrspacecast) on gfx950 — use plain swaps.
    float* inb  = bufA;
    float* outb = bufB;
    int Ln = 256, lsh = 7;
    for (int l = 0; l < 8; l++){
        {   // fused taps for layer l: thread t -> (c=t>>3, ci=t&7)
            int c = t >> 3, ci = t & 7;
            const float* w = wr + ((l*8 + c)*8 + ci)*3;
            float w0 = w[0], w1 = w[1], w2 = w[2];
            taps[t*4+0] = 0.5f*w0;
            taps[t*4+1] = 0.5f*(w0+w1);
            taps[t*4+2] = 0.5f*(w1+w2);
            taps[t*4+3] = 0.5f*w2;
        }
        __syncthreads();
        int Lo = Ln >> 1;
        for (int idx = t; idx < 8*Lo; idx += 64){
            int c = idx >> lsh, q = idx & (Lo-1);
            int j = 2*q;
            float acc = 0.f;
            #pragma unroll
            for (int ci = 0; ci < 8; ci++){
                const float* tp = &taps[(c*8+ci)*4];
                const float* h = &inb[ci*Ln];
                float hm1 = (j >= 1) ? h[j-1] : 0.f;
                float h0  = h[j];
                float h1  = h[j+1];
                float h2  = (j+2 < Ln) ? h[j+2] : 0.f;
                acc += tp[0]*hm1 + tp[1]*h0 + tp[2]*h1 + tp[3]*h2;
            }
            outb[c*Lo + q] = acc;
        }
        __syncthreads();
        float* tmp = inb; inb = outb; outb = tmp;
        Ln = Lo; lsh -= 1;
    }
    if (t < 8) Weff[t*512 + p] = inb[t];
}

// ---------------- Kernel 3: decode + histogram + contraction ----------------
__global__ __launch_bounds__(256) void cnn_main(
        const float* __restrict__ x,     // (512,512,20) f32 one-hot
        const float* __restrict__ Weff,  // (8,512)
        const float* __restrict__ U,     // (20,20)
        float* __restrict__ out){        // (512,20,8) f32
    int b = blockIdx.x;
    int t = threadIdx.x;
    __shared__ float W[8*512];
    __shared__ float Us[400];
    __shared__ float T[160];
    for (int idx = t; idx < 4096; idx += 256) W[idx] = Weff[idx];
    for (int idx = t; idx < 400; idx += 256) Us[idx] = U[idx];
    if (t < 160) T[t] = 0.f;
    __syncthreads();
    const float* xb = x + (size_t)b * (512*20);
    for (int p = t; p < 512; p += 256){
        const float4* f4 = (const float4*)(xb + p*20);   // 80B row, 16B aligned
        int aa = 0;
        #pragma unroll
        for (int j = 0; j < 5; j++){
            float4 v = f4[j];
            if (v.x != 0.f) aa = 4*j + 0;
            if (v.y != 0.f) aa = 4*j + 1;
            if (v.z != 0.f) aa = 4*j + 2;
            if (v.w != 0.f) aa = 4*j + 3;
        }
        #pragma unroll
        for (int c = 0; c < 8; c++){
            atomicAdd(&T[c*20 + aa], W[c*512 + p]);
        }
    }
    __syncthreads();
    if (t < 160){
        int k = t >> 3, c = t & 7;
        float acc = 0.f;
        #pragma unroll
        for (int i = 0; i < 20; i++) acc += T[c*20 + i] * Us[i*20 + k];
        out[(size_t)b*160 + t] = acc;   // out[b][k][c], t = k*8+c
    }
}

extern "C" void kernel_launch(void* const* d_in, const int* in_sizes, int n_in,
                              void* d_out, int out_size, void* d_ws, size_t ws_size,
                              hipStream_t stream){
    const float* x   = (const float*)d_in[0];
    // d_in[1] = masks (unused by forward)
    const float* lpm = (const float*)d_in[2];
    const float* pm  = (const float*)d_in[3];
    const float* wf  = (const float*)d_in[4];
    const float* wr  = (const float*)d_in[5];
    float* Weff = (float*)d_ws;          // 8*512 floats
    float* U    = Weff + 8*512;          // 400 floats

    hipLaunchKernelGGL(build_U,    dim3(1),   dim3(64),  0, stream, lpm, pm, U);
    hipLaunchKernelGGL(build_Weff, dim3(512), dim3(64),  0, stream, wf, wr, Weff);
    hipLaunchKernelGGL(cnn_main,   dim3(512), dim3(256), 0, stream, x, Weff, U,
                       (float*)d_out);
}

// Round 4
// 98.158 us; speedup vs baseline: 1.1354x; 1.1354x over previous
//
#include <hip/hip_runtime.h>

// B=512, L=512, A=20, C=8. All f32.
// Algebra: _row term == 0 (exp(-5000) underflows). One-hot x =>
// (xp+_column)[b,k,p] = U[aa[b,p],k], U = I + V (V from clip(lpm)*pm).
// Linear conv/pool stack => 8x512 matrix W_eff; out[b,k,c] =
//   sum_i T[b,c,i] * U[i,k],  T[b,c,i] = sum_{p: aa[b,p]=i} W_eff[c,p].
//
// W_eff built via impulse responses. Impulses stay SPARSE through the
// stack (support width <= 5), so each block tracks only an 8-wide window
// per channel instead of full-length buffers.

// ---------------- Kernel 1: W_eff, windowed impulse ----------------
__global__ __launch_bounds__(64) void build_Weff(
        const float* __restrict__ wf,   // (8,1,3)
        const float* __restrict__ wr,   // (8,8,8,3)
        float* __restrict__ Weff){      // (8,512)
    int p = blockIdx.x, t = threadIdx.x;
    int c = t >> 3, u = t & 7;          // channel, window slot
    __shared__ float winA[64];
    __shared__ float winB[64];
    __shared__ float taps[256];

    // stage 1: conv(1->8,k3,p1)+pool2 of impulse e_p. Fused 4-tap stride-2
    // conv, taps [w0, w0+w1, w1+w2, w2]*0.5. Output nonzero only where
    // 2q+j == p, j in [-1,2].
    int base = (p >> 1) - 1; if (base < 0) base = 0;
    {
        float w0 = wf[c*3+0], w1 = wf[c*3+1], w2 = wf[c*3+2];
        float tap0 = 0.5f*w0, tap1 = 0.5f*(w0+w1), tap2 = 0.5f*(w1+w2), tap3 = 0.5f*w2;
        int q = base + u;
        float v = 0.f;
        if (q < 256){
            int j = p - 2*q;
            if (j == -1) v = tap0;
            else if (j == 0) v = tap1;
            else if (j == 1) v = tap2;
            else if (j == 2) v = tap3;
        }
        winA[c*8+u] = v;
    }
    // NOTE: no LDS-pointer array initializers on gfx950 (addrspacecast in
    // static initializer is rejected) — plain pointer swap.
    float* inw  = winA;
    float* outw = winB;
    int Ln = 256;
    for (int l = 0; l < 8; l++){
        {   // layer taps: thread t -> (cc=t>>3, ci=t&7)
            const float* w = wr + ((l*8 + c)*8 + u)*3;
            float w0 = w[0], w1 = w[1], w2 = w[2];
            taps[t*4+0] = 0.5f*w0;
            taps[t*4+1] = 0.5f*(w0+w1);
            taps[t*4+2] = 0.5f*(w1+w2);
            taps[t*4+3] = 0.5f*w2;
        }
        __syncthreads();
        int Lo = Ln >> 1;
        int nb = (base - 2) >> 1; if (nb < 0) nb = 0;
        int q = nb + u;
        float acc = 0.f;
        if (q < Lo){
            #pragma unroll
            for (int ci = 0; ci < 8; ci++){
                const float* tp = &taps[(c*8+ci)*4];
                #pragma unroll
                for (int j = -1; j <= 2; j++){
                    int m  = 2*q + j;       // input position (global)
                    int wi = m - base;      // window index
                    float h = (m >= 0 && m < Ln && wi >= 0 && wi < 8)
                              ? inw[ci*8 + wi] : 0.f;
                    acc += tp[j+1] * h;
                }
            }
        }
        outw[c*8+u] = acc;
        float* tmp = inw; inw = outw; outw = tmp;
        base = nb; Ln = Lo;
        __syncthreads();
    }
    // final length 1, base == 0: answer at window slot 0
    if (u == 0) Weff[c*512 + p] = inw[c*8 + 0];
}

// ---------- Kernel 2: decode + per-wave histogram + inline-U epilogue ----------
__global__ __launch_bounds__(256) void cnn_main(
        const float* __restrict__ x,     // (512,512,20) f32 one-hot
        const float* __restrict__ Weff,  // (8,512)
        const float* __restrict__ lpm,   // (20,20)
        const float* __restrict__ pm,    // (20,20)
        float* __restrict__ out){        // (512,20,8) f32
    int b = blockIdx.x, t = threadIdx.x;
    __shared__ float W[4096];
    __shared__ float T[4][160];          // per-wave histograms
    __shared__ float Ts[160];
    for (int idx = t; idx < 4096; idx += 256) W[idx] = Weff[idx];
    for (int idx = t; idx < 640; idx += 256) (&T[0][0])[idx] = 0.f;
    __syncthreads();
    const float* xb = x + (size_t)b * 10240;
    int wid = t >> 6;
    for (int p = t; p < 512; p += 256){
        const float4* f4 = (const float4*)(xb + p*20);  // 80B rows, 16B aligned
        int aa = 0;
        #pragma unroll
        for (int j = 0; j < 5; j++){
            float4 v = f4[j];
            if (v.x != 0.f) aa = 4*j + 0;
            if (v.y != 0.f) aa = 4*j + 1;
            if (v.z != 0.f) aa = 4*j + 2;
            if (v.w != 0.f) aa = 4*j + 3;
        }
        #pragma unroll
        for (int c = 0; c < 8; c++)
            atomicAdd(&T[wid][c*20 + aa], W[c*512 + p]);
    }
    __syncthreads();
    if (t < 160) Ts[t] = T[0][t] + T[1][t] + T[2][t] + T[3][t];
    __syncthreads();
    if (t < 160){
        int k = t >> 3, c = t & 7;
        float acc = Ts[c*20 + k];              // U[k,k] = 1 (identity term)
        if (k != 19){                          // column 19 of V never written
            #pragma unroll
            for (int i = 0; i < 20; i++){
                if (i == k) continue;
                int r  = (i < k) ? i : k;
                int cc = (i < k) ? k : i;
                float l = fminf(fmaxf(lpm[r*20 + cc], 1e-3f), 1.0f);
                acc += Ts[c*20 + i] * (l * pm[r*20 + cc]);
            }
        }
        out[(size_t)b*160 + t] = acc;          // out[b][k][c], t = k*8+c
    }
}

extern "C" void kernel_launch(void* const* d_in, const int* in_sizes, int n_in,
                              void* d_out, int out_size, void* d_ws, size_t ws_size,
                              hipStream_t stream){
    const float* x   = (const float*)d_in[0];
    // d_in[1] = masks (unused by forward)
    const float* lpm = (const float*)d_in[2];
    const float* pm  = (const float*)d_in[3];
    const float* wf  = (const float*)d_in[4];
    const float* wr  = (const float*)d_in[5];
    float* Weff = (float*)d_ws;          // 8*512 floats

    hipLaunchKernelGGL(build_Weff, dim3(512), dim3(64),  0, stream, wf, wr, Weff);
    hipLaunchKernelGGL(cnn_main,   dim3(512), dim3(256), 0, stream, x, Weff, lpm, pm,
                       (float*)d_out);
}

// Round 5
// 91.493 us; speedup vs baseline: 1.2181x; 1.0729x over previous
//
#include <hip/hip_runtime.h>

// B=512, L=512, A=20, C=8. All f32.
// Algebra: _row term == 0 (exp(-5000) underflows). One-hot x =>
// (xp+_column)[b,k,p] = U[aa[b,p],k], U = I + V (V from clip(lpm)*pm,
// upper-tri mirrored, diag 0, col 19 never written).
// Linear conv/pool stack => 8x512 matrix W_eff; out[b,k,c] =
//   T[b,c,k] + sum_i T[b,c,i] * V[i,k],  T[b,c,i] = sum_{p: aa[b,p]=i} W_eff[c,p].
//
// W_eff built via impulse responses; impulses stay sparse (support <= 5),
// so each block tracks an 8-wide window per channel.

// ---------------- Kernel 1: W_eff, windowed impulse ----------------
__global__ __launch_bounds__(64) void build_Weff(
        const float* __restrict__ wf,   // (8,1,3)
        const float* __restrict__ wr,   // (8,8,8,3)
        float* __restrict__ Weff){      // (8,512)
    int p = blockIdx.x, t = threadIdx.x;
    int c = t >> 3, u = t & 7;          // channel, window slot
    __shared__ float winA[64];
    __shared__ float winB[64];
    __shared__ float taps[256];

    // Prefetch ALL levels' taps into registers up front: 24 independent
    // loads in flight at once (single-wave block can't hide per-level
    // load latency otherwise).
    float tw0[8], tw1[8], tw2[8];
    #pragma unroll
    for (int l = 0; l < 8; l++){
        const float* w = wr + ((l*8 + c)*8 + u)*3;
        tw0[l] = w[0]; tw1[l] = w[1]; tw2[l] = w[2];
    }

    // stage 1: conv(1->8,k3,p1)+pool2 of impulse e_p. Fused 4-tap stride-2
    // conv, taps [w0, w0+w1, w1+w2, w2]*0.5. Output nonzero only where
    // 2q+j == p, j in [-1,2].
    int base = (p >> 1) - 1; if (base < 0) base = 0;
    {
        float w0 = wf[c*3+0], w1 = wf[c*3+1], w2 = wf[c*3+2];
        float tap0 = 0.5f*w0, tap1 = 0.5f*(w0+w1), tap2 = 0.5f*(w1+w2), tap3 = 0.5f*w2;
        int q = base + u;
        float v = 0.f;
        if (q < 256){
            int j = p - 2*q;
            if (j == -1) v = tap0;
            else if (j == 0) v = tap1;
            else if (j == 1) v = tap2;
            else if (j == 2) v = tap3;
        }
        winA[c*8+u] = v;
    }
    // NOTE: no LDS-pointer array initializers on gfx950 (addrspacecast in
    // static initializer is rejected) — plain pointer swap.
    float* inw  = winA;
    float* outw = winB;
    int Ln = 256;
    for (int l = 0; l < 8; l++){
        {
            float w0 = tw0[l], w1 = tw1[l], w2 = tw2[l];
            taps[t*4+0] = 0.5f*w0;
            taps[t*4+1] = 0.5f*(w0+w1);
            taps[t*4+2] = 0.5f*(w1+w2);
            taps[t*4+3] = 0.5f*w2;
        }
        __syncthreads();
        int Lo = Ln >> 1;
        int nb = (base - 2) >> 1; if (nb < 0) nb = 0;
        int q = nb + u;
        float acc = 0.f;
        if (q < Lo){
            #pragma unroll
            for (int ci = 0; ci < 8; ci++){
                const float* tp = &taps[(c*8+ci)*4];
                #pragma unroll
                for (int j = -1; j <= 2; j++){
                    int m  = 2*q + j;       // input position (global)
                    int wi = m - base;      // window index
                    float h = (m >= 0 && m < Ln && wi >= 0 && wi < 8)
                              ? inw[ci*8 + wi] : 0.f;
                    acc += tp[j+1] * h;
                }
            }
        }
        outw[c*8+u] = acc;
        float* tmp = inw; inw = outw; outw = tmp;
        base = nb; Ln = Lo;
        __syncthreads();
    }
    // final length 1, base == 0: answer at window slot 0
    if (u == 0) Weff[c*512 + p] = inw[c*8 + 0];
}

// ---------- Kernel 2: decode + per-wave histogram + V epilogue ----------
__global__ __launch_bounds__(512) void cnn_main(
        const float* __restrict__ x,     // (512,512,20) f32 one-hot
        const float* __restrict__ Weff,  // (8,512)
        const float* __restrict__ lpm,   // (20,20)
        const float* __restrict__ pm,    // (20,20)
        float* __restrict__ out){        // (512,20,8) f32
    int b = blockIdx.x, t = threadIdx.x;
    __shared__ float W[4096];
    __shared__ float V[400];             // U minus identity (diag 0, col19 0)
    __shared__ float T[8][160];          // per-wave histograms
    __shared__ float Ts[160];
    // stage Weff with float4 (2 per thread)
    for (int idx = t; idx < 1024; idx += 512)
        ((float4*)W)[idx] = ((const float4*)Weff)[idx];
    // V table once per block (kills scattered lpm/pm reads in epilogue)
    if (t < 400){
        int i = t / 20, k = t % 20;
        float v = 0.f;
        if (k != 19 && k != i){
            int r  = (k > i) ? i : k;
            int cc = (k > i) ? k : i;
            float l = fminf(fmaxf(lpm[r*20 + cc], 1e-3f), 1.0f);
            v = l * pm[r*20 + cc];
        }
        V[t] = v;
    }
    for (int idx = t; idx < 1280; idx += 512) (&T[0][0])[idx] = 0.f;
    __syncthreads();

    const float* xb = x + (size_t)b * 10240;
    int wid = t >> 6;
    {   // one position per thread
        int p = t;
        const float4* f4 = (const float4*)(xb + p*20);  // 80B rows, 16B aligned
        int aa = 0;
        #pragma unroll
        for (int j = 0; j < 5; j++){
            float4 v = f4[j];
            if (v.x != 0.f) aa = 4*j + 0;
            if (v.y != 0.f) aa = 4*j + 1;
            if (v.z != 0.f) aa = 4*j + 2;
            if (v.w != 0.f) aa = 4*j + 3;
        }
        #pragma unroll
        for (int c = 0; c < 8; c++)
            atomicAdd(&T[wid][c*20 + aa], W[c*512 + p]);
    }
    __syncthreads();
    if (t < 160){
        float s = 0.f;
        #pragma unroll
        for (int w = 0; w < 8; w++) s += T[w][t];
        Ts[t] = s;
    }
    __syncthreads();
    if (t < 160){
        int k = t >> 3, c = t & 7;
        float acc = Ts[c*20 + k];              // identity term (U[k,k]=1)
        #pragma unroll
        for (int i = 0; i < 20; i++)
            acc += Ts[c*20 + i] * V[i*20 + k]; // V diag/col19 already 0
        out[(size_t)b*160 + t] = acc;          // out[b][k][c], t = k*8+c
    }
}

extern "C" void kernel_launch(void* const* d_in, const int* in_sizes, int n_in,
                              void* d_out, int out_size, void* d_ws, size_t ws_size,
                              hipStream_t stream){
    const float* x   = (const float*)d_in[0];
    // d_in[1] = masks (unused by forward)
    const float* lpm = (const float*)d_in[2];
    const float* pm  = (const float*)d_in[3];
    const float* wf  = (const float*)d_in[4];
    const float* wr  = (const float*)d_in[5];
    float* Weff = (float*)d_ws;          // 8*512 floats

    hipLaunchKernelGGL(build_Weff, dim3(512), dim3(64),  0, stream, wf, wr, Weff);
    hipLaunchKernelGGL(cnn_main,   dim3(512), dim3(512), 0, stream, x, Weff, lpm, pm,
                       (float*)d_out);
}